// Round 12
// baseline (69.592 us; speedup 1.0000x reference)
//
#include <hip/hip_runtime.h>

typedef __attribute__((ext_vector_type(8))) short s16x8;
typedef __attribute__((ext_vector_type(4))) float f32x4;
typedef __attribute__((ext_vector_type(4))) unsigned short u16x4;

#define FLAT 4096
#define CDIM 256
#define NB 2

// ws byte offsets
#define OFF_D1T  0u          // 4 MiB (t16-tiled bf16)
#define OFF_D2T  4194304u    // 4 MiB
#define OFF_PARTIAL 8388608u // 2*32*4096*4 = 1 MiB  (per-block column-min partials)
#define OFF_VIS  9502720u    // 8192 * 4
#define OFF_QUAD 9535488u    // 8192 * 16
#define OFF_RED  9666560u    // 64 doubles
#define OFF_CNT  9667072u    // done-counter
#define OFF_END  9667328u

// t16 layout: dT[b] is [FLAT/16 row-groups][CDIM/32 k-tiles][1KB tile], tile =
// [4 k-chunks(8 shorts)][16 rows][16B]; byte-identical to the LDS slab image so
// staging is ONE contiguous 1KB per global_load_lds (base + lane*16).
__device__ __forceinline__ size_t t16_off(int R, int lane) {
  return (size_t)(R >> 4) * 4096 + ((lane >> 3) * 512) + (((lane >> 1) & 3) * 128) +
         ((R & 15) * 8) + ((lane & 1) * 4);
}

__device__ __forceinline__ float bf2f(unsigned short u) {
  return __uint_as_float(((unsigned)u) << 16);
}
__device__ __forceinline__ unsigned short f2bf(float v) {
  unsigned u = __float_as_uint(v);
  return (unsigned short)((u + 0x7FFFu + ((u >> 16) & 1u)) >> 16);
}
__device__ __forceinline__ void async_g2l(const void* g, void* l) {
  __builtin_amdgcn_global_load_lds(
      (const __attribute__((address_space(1))) unsigned int*)g,
      (__attribute__((address_space(3))) unsigned int*)l,
      16, 0, 0);
}

// ---- pre: convert (0..255) + quads/counter (256) + vis (257..288) ----
__global__ __launch_bounds__(256) void k_pre(const float* __restrict__ desc1,
                                             const float* __restrict__ desc2,
                                             unsigned short* __restrict__ d1T,
                                             unsigned short* __restrict__ d2T,
                                             const void* __restrict__ mask,
                                             float* __restrict__ vispen,
                                             int4* __restrict__ quads,
                                             const float* __restrict__ homo,
                                             unsigned* __restrict__ cnt) {
  __shared__ __align__(16) unsigned ldsw[64 * 128];  // 32 KB, chunk-XOR swizzled
  int bid = blockIdx.x;
  int tid = threadIdx.x;
  if (bid < 256) {
    // ---- convert: desc[b][c][n] f32 -> t16-tiled bf16 via LDS transpose ----
    int x = bid & 63, which = (bid >> 6) & 1, b = bid >> 7;
    const float* src = (which ? desc2 : desc1) + (size_t)b * CDIM * FLAT;
    unsigned short* dst = (which ? d2T : d1T) + (size_t)b * FLAT * CDIM;
    int n0 = x * 64;
    int wv = tid >> 6, lane = tid & 63;
    const float* s0 = src + n0 + lane;
#pragma unroll 2
    for (int r = 0; r < 64; r += 8) {
      int c0 = wv * 64 + r;
      float v[8];
#pragma unroll
      for (int t = 0; t < 8; ++t) v[t] = s0[(size_t)(c0 + t) * FLAT];
      unsigned pk[4];
#pragma unroll
      for (int t = 0; t < 4; ++t) pk[t] = (unsigned)f2bf(v[2 * t]) | ((unsigned)f2bf(v[2 * t + 1]) << 16);
      int pg = (c0 >> 3) ^ (lane & 31);
      *(uint4*)(ldsw + lane * 128 + pg * 4) = make_uint4(pk[0], pk[1], pk[2], pk[3]);
    }
    __syncthreads();
    int n = wv * 16 + (lane & 15);
#pragma unroll 2
    for (int it = 0; it < 8; ++it) {
      int g = it * 4 + (lane >> 4);
      uint4 d = *(const uint4*)(ldsw + n * 128 + ((g ^ (n & 31)) * 4));
      *(uint4*)(dst + ((size_t)(n0 >> 4) + wv) * 4096 + it * 512 + lane * 8) = d;
    }
  } else if (bid == 256) {
    // ---- counter + quads (pure homography VALU) ----
    if (tid == 0) *cnt = 0u;
    for (int it = 0; it < 32; ++it) {
      int idx = it * 256 + tid;  // 0..8191
      int b = idx >> 12, n = idx & 4095;
      int i = n >> 6, j = n & 63;
      const float* Hm = homo + b * 9;
      float x = (float)(j * 8), y = (float)(i * 8);
      float den = Hm[6] * x + Hm[7] * y + Hm[8] + 1e-8f;
      float wxc = (Hm[0] * x + Hm[1] * y + Hm[2]) / den;
      float wyc = (Hm[3] * x + Hm[4] * y + Hm[5]) / den;
      int ic = min(63, max(0, (int)floorf(wyc * 0.125f)));
      int jc = min(63, max(0, (int)floorf(wxc * 0.125f)));
      int ul = ic * 64 + jc;
      int ur = (ul + 1 >= FLAT) ? ul : ul + 1;
      int ll = (ul + 64 >= FLAT) ? ul : ul + 64;
      int lr = (ll + 1 >= FLAT) ? ll : ll + 1;
      quads[idx] = make_int4(ul, ur, ll, lr);
    }
  } else {
    // ---- vis: mask dtype detect + 8x8 all() -> penalty 0/5 ----
    int idx = (bid - 257) * 256 + tid;  // 32 blocks -> 8192
    __shared__ int sflag;
    if (tid < 64) {
      const unsigned* mw = (const unsigned*)mask;
      int odd = 0;
#pragma unroll
      for (int t = 0; t < 16; ++t) {
        unsigned w = mw[tid * 16 + t];
        odd += (w > 1u && w != 0x3F800000u) ? 1 : 0;
      }
#pragma unroll
      for (int d = 32; d >= 1; d >>= 1) odd += __shfl_xor(odd, d, 64);
      if (tid == 0) sflag = (odd > 16) ? 1 : 0;  // 1 => byte-packed bools
    }
    __syncthreads();
    int b = idx >> 12, m = idx & 4095;
    int i = m >> 6, j = m & 63;
    bool ok = true;
    if (sflag) {
      const unsigned char* p = (const unsigned char*)mask + (size_t)b * 262144 + (size_t)(i * 8) * 512 + j * 8;
#pragma unroll
      for (int dy = 0; dy < 8; ++dy) {
        const unsigned* q = (const unsigned*)(p + (size_t)dy * 512);
        unsigned w0 = q[0], w1 = q[1];
        unsigned z0 = (w0 - 0x01010101u) & ~w0 & 0x80808080u;
        unsigned z1 = (w1 - 0x01010101u) & ~w1 & 0x80808080u;
        if (z0 | z1) ok = false;
      }
    } else {
      const unsigned* p = (const unsigned*)mask + (size_t)b * 262144 + (size_t)(i * 8) * 512 + j * 8;
#pragma unroll
      for (int dy = 0; dy < 8; ++dy) {
        const uint4* q = (const uint4*)(p + (size_t)dy * 512);
        uint4 u0 = q[0], u1 = q[1];
        if (!(u0.x && u0.y && u0.z && u0.w && u1.x && u1.y && u1.z && u1.w)) ok = false;
      }
    }
    vispen[idx] = ok ? 0.f : 5.f;
  }
}

// ---------------- min-GEMM: 256x128 tile, 8 waves, 3-deep counted-vmcnt --------
// Round-6 verified loop, verbatim.
__global__ __launch_bounds__(512, 4) void k_gemm(const unsigned short* __restrict__ d1T,
                                                 const unsigned short* __restrict__ d2T,
                                                 const int4* __restrict__ quads,
                                                 const float* __restrict__ vispen,
                                                 float* __restrict__ partial) {
  __shared__ __align__(16) char lds[3][24576];  // per buf: A tiles 0..15 (16KB), B tiles 0..7 (8KB)
  // XCD-chunked swizzle (nwg=1024, %8==0 -> bijective)
  int lin = blockIdx.x;
  int id = (lin & 7) * 128 + (lin >> 3);
  int b = id >> 9;
  int mn = id & 511;
  int m0 = (mn & 31) << 7;   // cols (desc2), 32 m-blocks of 128
  int n0 = (mn >> 5) << 8;   // rows (desc1), 16 n-blocks of 256
  int tid = threadIdx.x;
  int wid = tid >> 6, lane = tid & 63;
  int wr = wid >> 1, wc = wid & 1;  // 4x2 wave grid of 64x64 tiles
  int lg = lane >> 4, ll16 = lane & 15;

  const unsigned short* Ab = d1T + (size_t)b * FLAT * CDIM;
  const unsigned short* Bb = d2T + (size_t)b * FLAT * CDIM;

  // wave wid stages tiles idx = wid*3 .. wid*3+2 (24 total: 16 A + 8 B);
  // each source is a CONTIGUOUS 1KB t16 tile: base + lane*16B.
  const unsigned short* srcq[3];
  int ldsoff[3];
#pragma unroll
  for (int q = 0; q < 3; ++q) {
    int idx = wid * 3 + q;      // 0..23
    int isA = idx < 16;
    int s = isA ? idx : idx - 16;
    int rg = (((isA ? n0 : m0)) >> 4) + s;
    srcq[q] = (isA ? Ab : Bb) + (size_t)rg * 4096 + lane * 8;
    ldsoff[q] = (isA ? 0 : 16384) + s * 1024;
  }

  f32x4 acc[4][4] = {};

#define STAGE(t, p)                                            \
  {                                                            \
    _Pragma("unroll") for (int q = 0; q < 3; ++q)              \
        async_g2l(srcq[q] + (t) * 512, &lds[p][ldsoff[q]]);    \
  }

#define KSTEP(T, WN)                                                                \
  {                                                                                 \
    asm volatile("s_waitcnt vmcnt(" #WN ")" ::: "memory");                          \
    __builtin_amdgcn_s_barrier();                                                   \
    const char* base_ = lds[(T) % 3];                                               \
    s16x8 af[4], bf[4];                                                             \
    _Pragma("unroll") for (int mi = 0; mi < 4; ++mi)                                \
        af[mi] = *(const s16x8*)(base_ + (wr * 4 + mi) * 1024 + lane * 16);         \
    _Pragma("unroll") for (int ni = 0; ni < 4; ++ni)                                \
        bf[ni] = *(const s16x8*)(base_ + 16384 + (wc * 4 + ni) * 1024 + lane * 16); \
    _Pragma("unroll") for (int mi = 0; mi < 4; ++mi)                                \
      _Pragma("unroll") for (int ni = 0; ni < 4; ++ni)                              \
          acc[mi][ni] =                                                             \
              __builtin_amdgcn_mfma_f32_16x16x32_bf16(af[mi], bf[ni], acc[mi][ni], 0, 0, 0); \
    asm volatile("s_waitcnt lgkmcnt(0)" ::: "memory");                              \
    __builtin_amdgcn_s_barrier();                                                   \
    if ((T) < 5) STAGE((T) + 3, ((T) + 3) % 3);                                     \
  }

  STAGE(0, 0);
  STAGE(1, 1);
  STAGE(2, 2);
  KSTEP(0, 6) KSTEP(1, 6) KSTEP(2, 6) KSTEP(3, 6)
  KSTEP(4, 6) KSTEP(5, 6) KSTEP(6, 3) KSTEP(7, 0)
#undef KSTEP
#undef STAGE

  // epilogue: penalties + column-min; cross-wave combine in LDS; one plain
  // coalesced store per row (no atomics).
  const int4* qB = quads + b * FLAT;
  const float* vB = vispen + b * FLAT;
  float* red = (float*)lds;  // 256 rows x 2 col-halves
  float pv[4];
#pragma unroll
  for (int ni = 0; ni < 4; ++ni) pv[ni] = vB[m0 + wc * 64 + ni * 16 + ll16];
#pragma unroll
  for (int mi = 0; mi < 4; ++mi) {
    int rowBase = wr * 64 + mi * 16 + lg * 4;
    float rm[4] = {1e30f, 1e30f, 1e30f, 1e30f};
    int4 q0 = qB[n0 + rowBase + 0];
    int4 q1 = qB[n0 + rowBase + 1];
    int4 q2 = qB[n0 + rowBase + 2];
    int4 q3 = qB[n0 + rowBase + 3];
#pragma unroll
    for (int ni = 0; ni < 4; ++ni) {
      int gm = m0 + wc * 64 + ni * 16 + ll16;
      f32x4 a = acc[mi][ni];
      float v0 = 2.f - 2.f * a[0] + pv[ni] + ((gm == q0.x || gm == q0.y || gm == q0.z || gm == q0.w) ? 5.f : 0.f);
      float v1 = 2.f - 2.f * a[1] + pv[ni] + ((gm == q1.x || gm == q1.y || gm == q1.z || gm == q1.w) ? 5.f : 0.f);
      float v2 = 2.f - 2.f * a[2] + pv[ni] + ((gm == q2.x || gm == q2.y || gm == q2.z || gm == q2.w) ? 5.f : 0.f);
      float v3 = 2.f - 2.f * a[3] + pv[ni] + ((gm == q3.x || gm == q3.y || gm == q3.z || gm == q3.w) ? 5.f : 0.f);
      rm[0] = fminf(rm[0], v0);
      rm[1] = fminf(rm[1], v1);
      rm[2] = fminf(rm[2], v2);
      rm[3] = fminf(rm[3], v3);
    }
#pragma unroll
    for (int r = 0; r < 4; ++r) {
      float v = rm[r];
#pragma unroll
      for (int d = 1; d < 16; d <<= 1) v = fminf(v, __shfl_xor(v, d, 64));
      if (ll16 == 0) red[(rowBase + r) * 2 + wc] = v;
    }
  }
  __syncthreads();
  if ((wid & 1) == 0) {  // waves 0,2,4,6 -> rows wr*64..+63
    int row = wr * 64 + lane;
    float v = fminf(red[row * 2], red[row * 2 + 1]);
    partial[((size_t)(b * 32 + (m0 >> 7))) * FLAT + n0 + row] = v;
  }
}

// ---- redfin: inline pos/wv (per-thread bilinear dot) + 32-way min + loss ----
__global__ void k_redfin(const unsigned short* __restrict__ d1T,
                         const unsigned short* __restrict__ d2T,
                         const float* __restrict__ homo,
                         const float* __restrict__ partial,
                         double* __restrict__ part,
                         unsigned* __restrict__ cnt, float* __restrict__ out) {
  int tid = threadIdx.x;
  int bid = blockIdx.x;
  int idx = bid * 256 + tid;  // grid 32 -> 8192
  int wid = tid >> 6, lane = tid & 63;
  int b = idx >> 12, n = idx & 4095;

  // ---- pos/wv inline (was k_setup; per-thread full 256-ch dot) ----
  int i = n >> 6, j = n & 63;
  const float* Hm = homo + b * 9;
  float x = (float)(j * 8), y = (float)(i * 8);
  float den = Hm[6] * x + Hm[7] * y + Hm[8] + 1e-8f;
  float wxc = (Hm[0] * x + Hm[1] * y + Hm[2]) / den;
  float wyc = (Hm[3] * x + Hm[4] * y + Hm[5]) / den;
  float w = (wyc >= 0.f && wyc < 512.f && wxc >= 0.f && wxc < 512.f) ? 1.f : 0.f;
  float cy = fminf(fmaxf(wyc * 0.125f, 0.f), 63.f);
  float cx = fminf(fmaxf(wxc * 0.125f, 0.f), 63.f);
  float y0 = floorf(cy), x0 = floorf(cx);
  float y1 = fminf(y0 + 1.f, 63.f), x1 = fminf(x0 + 1.f, 63.f);
  float fy = cy - y0, fx = cx - x0;
  float w00 = (1.f - fy) * (1.f - fx), w01 = (1.f - fy) * fx;
  float w10 = fy * (1.f - fx), w11 = fy * fx;
  int m00 = (int)y0 * 64 + (int)x0;
  int m01 = (int)y0 * 64 + (int)x1;
  int m10 = (int)y1 * 64 + (int)x0;
  int m11 = (int)y1 * 64 + (int)x1;

  const unsigned short* A = d1T + (size_t)b * FLAT * CDIM;
  const unsigned short* B = d2T + (size_t)b * FLAT * CDIM;
  // t16 piece addressing: row R, piece p(0..31) at (R>>4)*4096 + (p>>2)*512 +
  // (p&3)*128 + (R&15)*8, 8 shorts. 16 consecutive threads (rows) read 16B-
  // adjacent pieces -> coalesced 256B bursts.
  size_t baseA = (size_t)(n >> 4) * 4096 + (n & 15) * 8;
  size_t b00 = (size_t)(m00 >> 4) * 4096 + (m00 & 15) * 8;
  size_t b01 = (size_t)(m01 >> 4) * 4096 + (m01 & 15) * 8;
  size_t b10 = (size_t)(m10 >> 4) * 4096 + (m10 & 15) * 8;
  size_t b11 = (size_t)(m11 >> 4) * 4096 + (m11 & 15) * 8;
  float s = 0.f;
#pragma unroll 4
  for (int p = 0; p < 32; ++p) {
    size_t off = (size_t)(p >> 2) * 512 + (p & 3) * 128;
    u16x4 a0 = *(const u16x4*)(A + baseA + off);
    u16x4 a1 = *(const u16x4*)(A + baseA + off + 4);
    u16x4 c00 = *(const u16x4*)(B + b00 + off);
    u16x4 c00b = *(const u16x4*)(B + b00 + off + 4);
    u16x4 c01 = *(const u16x4*)(B + b01 + off);
    u16x4 c01b = *(const u16x4*)(B + b01 + off + 4);
    u16x4 c10 = *(const u16x4*)(B + b10 + off);
    u16x4 c10b = *(const u16x4*)(B + b10 + off + 4);
    u16x4 c11 = *(const u16x4*)(B + b11 + off);
    u16x4 c11b = *(const u16x4*)(B + b11 + off + 4);
#pragma unroll
    for (int t = 0; t < 4; ++t) {
      float vt = w00 * bf2f(c00[t]) + w01 * bf2f(c01[t]) + w10 * bf2f(c10[t]) + w11 * bf2f(c11[t]);
      s += bf2f(a0[t]) * vt;
      float vu = w00 * bf2f(c00b[t]) + w01 * bf2f(c01b[t]) + w10 * bf2f(c10b[t]) + w11 * bf2f(c11b[t]);
      s += bf2f(a1[t]) * vu;
    }
  }
  float p = 2.f - 2.f * s;

  // ---- neg over 32 m-chunks + loss ----
  const float* ps = partial + (size_t)b * 32 * FLAT + n;
  float neg = 1e30f;
#pragma unroll
  for (int sc = 0; sc < 32; ++sc) neg = fminf(neg, ps[(size_t)sc * FLAT]);
  float t = fmaxf(p - neg + 1.f, 0.f);
  double aL = (double)(t * t) * (double)w;
  double aW = (double)w;
#pragma unroll
  for (int d = 32; d >= 1; d >>= 1) {
    aL += __shfl_xor(aL, d, 64);
    aW += __shfl_xor(aW, d, 64);
  }
  __shared__ double red[8];
  __shared__ int lastFlag;
  if (lane == 0) { red[wid * 2] = aL; red[wid * 2 + 1] = aW; }
  __syncthreads();
  if (tid == 0) {
    double L = 0.0, W = 0.0;
#pragma unroll
    for (int u = 0; u < 4; ++u) { L += red[u * 2]; W += red[u * 2 + 1]; }
    part[bid * 2] = L;
    part[bid * 2 + 1] = W;
    __threadfence();
    unsigned old = atomicAdd(cnt, 1u);
    lastFlag = (old == 31u) ? 1 : 0;
  }
  __syncthreads();
  if (lastFlag && wid == 0) {
    double L = 0.0, W = 0.0;
    if (lane < 32) { L = part[2 * lane]; W = part[2 * lane + 1]; }
#pragma unroll
    for (int d = 16; d >= 1; d >>= 1) {
      L += __shfl_xor(L, d, 64);
      W += __shfl_xor(W, d, 64);
    }
    if (lane == 0) out[0] = (float)(L / W);
  }
}

extern "C" void kernel_launch(void* const* d_in, const int* in_sizes, int n_in,
                              void* d_out, int out_size, void* d_ws, size_t ws_size,
                              hipStream_t stream) {
  if (ws_size < OFF_END) return;
  const float* desc1 = (const float*)d_in[0];
  const float* desc2 = (const float*)d_in[1];
  const float* homo = (const float*)d_in[2];
  const void* mask = d_in[3];

  char* ws = (char*)d_ws;
  unsigned short* d1T = (unsigned short*)(ws + OFF_D1T);
  unsigned short* d2T = (unsigned short*)(ws + OFF_D2T);
  float* partial = (float*)(ws + OFF_PARTIAL);
  float* vispen = (float*)(ws + OFF_VIS);
  int4* quads = (int4*)(ws + OFF_QUAD);
  double* part = (double*)(ws + OFF_RED);
  unsigned* cnt = (unsigned*)(ws + OFF_CNT);
  float* out = (float*)d_out;

  k_pre<<<dim3(289), dim3(256), 0, stream>>>(desc1, desc2, d1T, d2T, mask, vispen, quads, homo, cnt);
  k_gemm<<<dim3(1024), dim3(512), 0, stream>>>(d1T, d2T, quads, vispen, partial);
  k_redfin<<<dim3(32), dim3(256), 0, stream>>>(d1T, d2T, homo, partial, part, cnt, out);
}

// Round 13
// 56.697 us; speedup vs baseline: 1.2274x; 1.2274x over previous
//
#include <hip/hip_runtime.h>

typedef __attribute__((ext_vector_type(8))) short s16x8;
typedef __attribute__((ext_vector_type(4))) float f32x4;
typedef __attribute__((ext_vector_type(4))) unsigned short u16x4;

#define FLAT 4096
#define CDIM 256
#define NB 2

// ws byte offsets
#define OFF_D1T  0u          // 4 MiB (t16-tiled bf16)
#define OFF_D2T  4194304u    // 4 MiB
#define OFF_PARTIAL 8388608u // 2*32*4096*4 = 1 MiB  (per-block column-min partials)
#define OFF_POS  9437184u    // 8192 * 4
#define OFF_WV   9469952u    // 8192 * 4
#define OFF_VIS  9502720u    // 8192 * 4
#define OFF_QUAD 9535488u    // 8192 * 16
#define OFF_RED  9666560u    // 64 doubles
#define OFF_CNT  9667072u    // done-counter
#define OFF_END  9667328u

// t16 layout: dT[b] is [FLAT/16 row-groups][CDIM/32 k-tiles][1KB tile], tile =
// [4 k-chunks(8 shorts)][16 rows][16B]; byte-identical to the LDS slab image so
// staging is ONE contiguous 1KB per global_load_lds (base + lane*16).
__device__ __forceinline__ size_t t16_off(int R, int lane) {
  return (size_t)(R >> 4) * 4096 + ((lane >> 3) * 512) + (((lane >> 1) & 3) * 128) +
         ((R & 15) * 8) + ((lane & 1) * 4);
}

__device__ __forceinline__ float bf2f(unsigned short u) {
  return __uint_as_float(((unsigned)u) << 16);
}
__device__ __forceinline__ unsigned short f2bf(float v) {
  unsigned u = __float_as_uint(v);
  return (unsigned short)((u + 0x7FFFu + ((u >> 16) & 1u)) >> 16);
}
__device__ __forceinline__ void async_g2l(const void* g, void* l) {
  __builtin_amdgcn_global_load_lds(
      (const __attribute__((address_space(1))) unsigned int*)g,
      (__attribute__((address_space(3))) unsigned int*)l,
      16, 0, 0);
}

// ---------------- pre: convert (blocks 0..255) + vis/init (blocks 256..287) ----
__global__ __launch_bounds__(256) void k_pre(const float* __restrict__ desc1,
                                             const float* __restrict__ desc2,
                                             unsigned short* __restrict__ d1T,
                                             unsigned short* __restrict__ d2T,
                                             const void* __restrict__ mask,
                                             float* __restrict__ vispen,
                                             unsigned* __restrict__ cnt) {
  __shared__ __align__(16) unsigned ldsw[64 * 128];  // 32 KB, chunk-XOR swizzled
  int bid = blockIdx.x;
  int tid = threadIdx.x;
  if (bid < 256) {
    // ---- convert: desc[b][c][n] f32 -> t16-tiled bf16 via LDS transpose ----
    int x = bid & 63, which = (bid >> 6) & 1, b = bid >> 7;
    const float* src = (which ? desc2 : desc1) + (size_t)b * CDIM * FLAT;
    unsigned short* dst = (which ? d2T : d1T) + (size_t)b * FLAT * CDIM;
    int n0 = x * 64;
    int wv = tid >> 6, lane = tid & 63;
    const float* s0 = src + n0 + lane;
#pragma unroll 2
    for (int r = 0; r < 64; r += 8) {
      int c0 = wv * 64 + r;
      float v[8];
#pragma unroll
      for (int t = 0; t < 8; ++t) v[t] = s0[(size_t)(c0 + t) * FLAT];
      unsigned pk[4];
#pragma unroll
      for (int t = 0; t < 4; ++t) pk[t] = (unsigned)f2bf(v[2 * t]) | ((unsigned)f2bf(v[2 * t + 1]) << 16);
      int pg = (c0 >> 3) ^ (lane & 31);
      *(uint4*)(ldsw + lane * 128 + pg * 4) = make_uint4(pk[0], pk[1], pk[2], pk[3]);
    }
    __syncthreads();
    int n = wv * 16 + (lane & 15);
#pragma unroll 2
    for (int it = 0; it < 8; ++it) {
      int g = it * 4 + (lane >> 4);
      uint4 d = *(const uint4*)(ldsw + n * 128 + ((g ^ (n & 31)) * 4));
      *(uint4*)(dst + ((size_t)(n0 >> 4) + wv) * 4096 + it * 512 + lane * 8) = d;
    }
  } else {
    // ---- vis: mask dtype detect + 8x8 all() -> penalty 0/5; zero counter ----
    int idx = (bid - 256) * 256 + tid;  // 32 blocks -> 8192
    if (idx == 0) *cnt = 0u;
    __shared__ int sflag;
    if (tid < 64) {
      const unsigned* mw = (const unsigned*)mask;
      int odd = 0;
#pragma unroll
      for (int t = 0; t < 16; ++t) {
        unsigned w = mw[tid * 16 + t];
        odd += (w > 1u && w != 0x3F800000u) ? 1 : 0;
      }
#pragma unroll
      for (int d = 32; d >= 1; d >>= 1) odd += __shfl_xor(odd, d, 64);
      if (tid == 0) sflag = (odd > 16) ? 1 : 0;  // 1 => byte-packed bools
    }
    __syncthreads();
    int b = idx >> 12, m = idx & 4095;
    int i = m >> 6, j = m & 63;
    bool ok = true;
    if (sflag) {
      const unsigned char* p = (const unsigned char*)mask + (size_t)b * 262144 + (size_t)(i * 8) * 512 + j * 8;
#pragma unroll
      for (int dy = 0; dy < 8; ++dy) {
        const unsigned* q = (const unsigned*)(p + (size_t)dy * 512);
        unsigned w0 = q[0], w1 = q[1];
        unsigned z0 = (w0 - 0x01010101u) & ~w0 & 0x80808080u;
        unsigned z1 = (w1 - 0x01010101u) & ~w1 & 0x80808080u;
        if (z0 | z1) ok = false;
      }
    } else {
      const unsigned* p = (const unsigned*)mask + (size_t)b * 262144 + (size_t)(i * 8) * 512 + j * 8;
#pragma unroll
      for (int dy = 0; dy < 8; ++dy) {
        const uint4* q = (const uint4*)(p + (size_t)dy * 512);
        uint4 u0 = q[0], u1 = q[1];
        if (!(u0.x && u0.y && u0.z && u0.w && u1.x && u1.y && u1.z && u1.w)) ok = false;
      }
    }
    vispen[idx] = ok ? 0.f : 5.f;
  }
}

// ---------------- setup: warp coords, wv, quad indices, pos (bilinear dot) ------
__global__ void k_setup(const float* __restrict__ homo, const unsigned short* __restrict__ d1T,
                        const unsigned short* __restrict__ d2T, float* __restrict__ pos,
                        float* __restrict__ wv, int4* __restrict__ quads) {
  int b = blockIdx.z;
  int tid = threadIdx.x;
  int wid = tid >> 6, lane = tid & 63;
  int n = blockIdx.x * 4 + wid;
  int i = n >> 6, j = n & 63;
  const float* Hm = homo + b * 9;
  float x = (float)(j * 8), y = (float)(i * 8);
  float den = Hm[6] * x + Hm[7] * y + Hm[8] + 1e-8f;
  float wxc = (Hm[0] * x + Hm[1] * y + Hm[2]) / den;
  float wyc = (Hm[3] * x + Hm[4] * y + Hm[5]) / den;

  float vv = (wyc >= 0.f && wyc < 512.f && wxc >= 0.f && wxc < 512.f) ? 1.f : 0.f;

  int ic = min(63, max(0, (int)floorf(wyc * 0.125f)));
  int jc = min(63, max(0, (int)floorf(wxc * 0.125f)));
  int ul = ic * 64 + jc;
  int ur = (ul + 1 >= FLAT) ? ul : ul + 1;
  int ll = (ul + 64 >= FLAT) ? ul : ul + 64;
  int lr = (ll + 1 >= FLAT) ? ll : ll + 1;

  float cy = fminf(fmaxf(wyc * 0.125f, 0.f), 63.f);
  float cx = fminf(fmaxf(wxc * 0.125f, 0.f), 63.f);
  float y0 = floorf(cy), x0 = floorf(cx);
  float y1 = fminf(y0 + 1.f, 63.f), x1 = fminf(x0 + 1.f, 63.f);
  float fy = cy - y0, fx = cx - x0;
  float w00 = (1.f - fy) * (1.f - fx), w01 = (1.f - fy) * fx;
  float w10 = fy * (1.f - fx), w11 = fy * fx;
  int m00 = (int)y0 * 64 + (int)x0;
  int m01 = (int)y0 * 64 + (int)x1;
  int m10 = (int)y1 * 64 + (int)x0;
  int m11 = (int)y1 * 64 + (int)x1;

  size_t base = (size_t)b * FLAT * CDIM;
  u16x4 a   = *(const u16x4*)(d1T + base + t16_off(n, lane));
  u16x4 v00 = *(const u16x4*)(d2T + base + t16_off(m00, lane));
  u16x4 v01 = *(const u16x4*)(d2T + base + t16_off(m01, lane));
  u16x4 v10 = *(const u16x4*)(d2T + base + t16_off(m10, lane));
  u16x4 v11 = *(const u16x4*)(d2T + base + t16_off(m11, lane));
  float s = 0.f;
#pragma unroll
  for (int t = 0; t < 4; ++t) {
    float vt = w00 * bf2f(v00[t]) + w01 * bf2f(v01[t]) + w10 * bf2f(v10[t]) + w11 * bf2f(v11[t]);
    s += bf2f(a[t]) * vt;
  }
#pragma unroll
  for (int d = 32; d >= 1; d >>= 1) s += __shfl_xor(s, d, 64);
  if (lane == 0) {
    int idx = b * FLAT + n;
    pos[idx] = 2.f - 2.f * s;
    wv[idx] = vv;
    quads[idx] = make_int4(ul, ur, ll, lr);
  }
}

// ---------------- min-GEMM: 256x128 tile, 8 waves, 2-deep counted-vmcnt --------
// Round-6 loop with ONE isolated change: 3 LDS buffers -> 2 (72KB -> 48KB) so
// 3 blocks/CU co-reside (was 2). Counted-vmcnt invariant at depth 2: at step T,
// 6 loads outstanding -> vmcnt(3) retires exactly stage T.
__global__ __launch_bounds__(512, 4) void k_gemm(const unsigned short* __restrict__ d1T,
                                                 const unsigned short* __restrict__ d2T,
                                                 const int4* __restrict__ quads,
                                                 const float* __restrict__ vispen,
                                                 float* __restrict__ partial) {
  __shared__ __align__(16) char lds[2][24576];  // per buf: A tiles 0..15 (16KB), B tiles 0..7 (8KB)
  // XCD-chunked swizzle (nwg=1024, %8==0 -> bijective)
  int lin = blockIdx.x;
  int id = (lin & 7) * 128 + (lin >> 3);
  int b = id >> 9;
  int mn = id & 511;
  int m0 = (mn & 31) << 7;   // cols (desc2), 32 m-blocks of 128
  int n0 = (mn >> 5) << 8;   // rows (desc1), 16 n-blocks of 256
  int tid = threadIdx.x;
  int wid = tid >> 6, lane = tid & 63;
  int wr = wid >> 1, wc = wid & 1;  // 4x2 wave grid of 64x64 tiles
  int lg = lane >> 4, ll16 = lane & 15;

  const unsigned short* Ab = d1T + (size_t)b * FLAT * CDIM;
  const unsigned short* Bb = d2T + (size_t)b * FLAT * CDIM;

  // wave wid stages tiles idx = wid*3 .. wid*3+2 (24 total: 16 A + 8 B);
  // each source is a CONTIGUOUS 1KB t16 tile: base + lane*16B.
  const unsigned short* srcq[3];
  int ldsoff[3];
#pragma unroll
  for (int q = 0; q < 3; ++q) {
    int idx = wid * 3 + q;      // 0..23
    int isA = idx < 16;
    int s = isA ? idx : idx - 16;
    int rg = (((isA ? n0 : m0)) >> 4) + s;
    srcq[q] = (isA ? Ab : Bb) + (size_t)rg * 4096 + lane * 8;
    ldsoff[q] = (isA ? 0 : 16384) + s * 1024;
  }

  f32x4 acc[4][4] = {};

#define STAGE(t, p)                                            \
  {                                                            \
    _Pragma("unroll") for (int q = 0; q < 3; ++q)              \
        async_g2l(srcq[q] + (t) * 512, &lds[p][ldsoff[q]]);    \
  }

#define KSTEP(T, WN)                                                                \
  {                                                                                 \
    asm volatile("s_waitcnt vmcnt(" #WN ")" ::: "memory");                          \
    __builtin_amdgcn_s_barrier();                                                   \
    const char* base_ = lds[(T) & 1];                                               \
    s16x8 af[4], bf[4];                                                             \
    _Pragma("unroll") for (int mi = 0; mi < 4; ++mi)                                \
        af[mi] = *(const s16x8*)(base_ + (wr * 4 + mi) * 1024 + lane * 16);         \
    _Pragma("unroll") for (int ni = 0; ni < 4; ++ni)                                \
        bf[ni] = *(const s16x8*)(base_ + 16384 + (wc * 4 + ni) * 1024 + lane * 16); \
    _Pragma("unroll") for (int mi = 0; mi < 4; ++mi)                                \
      _Pragma("unroll") for (int ni = 0; ni < 4; ++ni)                              \
          acc[mi][ni] =                                                             \
              __builtin_amdgcn_mfma_f32_16x16x32_bf16(af[mi], bf[ni], acc[mi][ni], 0, 0, 0); \
    asm volatile("s_waitcnt lgkmcnt(0)" ::: "memory");                              \
    __builtin_amdgcn_s_barrier();                                                   \
    if ((T) < 6) STAGE((T) + 2, ((T) + 2) & 1);                                     \
  }

  STAGE(0, 0);
  STAGE(1, 1);
  KSTEP(0, 3) KSTEP(1, 3) KSTEP(2, 3) KSTEP(3, 3)
  KSTEP(4, 3) KSTEP(5, 3) KSTEP(6, 3) KSTEP(7, 0)
#undef KSTEP
#undef STAGE

  // epilogue: penalties + column-min; cross-wave combine in LDS; one plain
  // coalesced store per row (no atomics).
  const int4* qB = quads + b * FLAT;
  const float* vB = vispen + b * FLAT;
  float* red = (float*)lds;  // 256 rows x 2 col-halves
  float pv[4];
#pragma unroll
  for (int ni = 0; ni < 4; ++ni) pv[ni] = vB[m0 + wc * 64 + ni * 16 + ll16];
#pragma unroll
  for (int mi = 0; mi < 4; ++mi) {
    int rowBase = wr * 64 + mi * 16 + lg * 4;
    float rm[4] = {1e30f, 1e30f, 1e30f, 1e30f};
    int4 q0 = qB[n0 + rowBase + 0];
    int4 q1 = qB[n0 + rowBase + 1];
    int4 q2 = qB[n0 + rowBase + 2];
    int4 q3 = qB[n0 + rowBase + 3];
#pragma unroll
    for (int ni = 0; ni < 4; ++ni) {
      int gm = m0 + wc * 64 + ni * 16 + ll16;
      f32x4 a = acc[mi][ni];
      float v0 = 2.f - 2.f * a[0] + pv[ni] + ((gm == q0.x || gm == q0.y || gm == q0.z || gm == q0.w) ? 5.f : 0.f);
      float v1 = 2.f - 2.f * a[1] + pv[ni] + ((gm == q1.x || gm == q1.y || gm == q1.z || gm == q1.w) ? 5.f : 0.f);
      float v2 = 2.f - 2.f * a[2] + pv[ni] + ((gm == q2.x || gm == q2.y || gm == q2.z || gm == q2.w) ? 5.f : 0.f);
      float v3 = 2.f - 2.f * a[3] + pv[ni] + ((gm == q3.x || gm == q3.y || gm == q3.z || gm == q3.w) ? 5.f : 0.f);
      rm[0] = fminf(rm[0], v0);
      rm[1] = fminf(rm[1], v1);
      rm[2] = fminf(rm[2], v2);
      rm[3] = fminf(rm[3], v3);
    }
#pragma unroll
    for (int r = 0; r < 4; ++r) {
      float v = rm[r];
#pragma unroll
      for (int d = 1; d < 16; d <<= 1) v = fminf(v, __shfl_xor(v, d, 64));
      if (ll16 == 0) red[(rowBase + r) * 2 + wc] = v;
    }
  }
  __syncthreads();
  if ((wid & 1) == 0) {  // waves 0,2,4,6 -> rows wr*64..+63
    int row = wr * 64 + lane;
    float v = fminf(red[row * 2], red[row * 2 + 1]);
    partial[((size_t)(b * 32 + (m0 >> 7))) * FLAT + n0 + row] = v;
  }
}

// ---------------- reduce partials + loss; last block finalizes ----------------
__global__ void k_redfin(const float* __restrict__ partial, const float* __restrict__ pos,
                         const float* __restrict__ wv, double* __restrict__ part,
                         unsigned* __restrict__ cnt, float* __restrict__ out) {
  int tid = threadIdx.x;
  int bid = blockIdx.x;
  int idx = bid * 256 + tid;  // grid 32 -> 8192
  int wid = tid >> 6, lane = tid & 63;
  int b = idx >> 12, nl = idx & 4095;
  const float* ps = partial + (size_t)b * 32 * FLAT + nl;
  float neg = 1e30f;
#pragma unroll
  for (int s = 0; s < 32; ++s) neg = fminf(neg, ps[(size_t)s * FLAT]);
  float p = pos[idx], w = wv[idx];
  float t = fmaxf(p - neg + 1.f, 0.f);
  double aL = (double)(t * t) * (double)w;
  double aW = (double)w;
#pragma unroll
  for (int d = 32; d >= 1; d >>= 1) {
    aL += __shfl_xor(aL, d, 64);
    aW += __shfl_xor(aW, d, 64);
  }
  __shared__ double red[8];
  __shared__ int lastFlag;
  if (lane == 0) { red[wid * 2] = aL; red[wid * 2 + 1] = aW; }
  __syncthreads();
  if (tid == 0) {
    double L = 0.0, W = 0.0;
#pragma unroll
    for (int u = 0; u < 4; ++u) { L += red[u * 2]; W += red[u * 2 + 1]; }
    part[bid * 2] = L;
    part[bid * 2 + 1] = W;
    __threadfence();
    unsigned old = atomicAdd(cnt, 1u);
    lastFlag = (old == 31u) ? 1 : 0;
  }
  __syncthreads();
  if (lastFlag && wid == 0) {
    double L = 0.0, W = 0.0;
    if (lane < 32) { L = part[2 * lane]; W = part[2 * lane + 1]; }
#pragma unroll
    for (int d = 16; d >= 1; d >>= 1) {
      L += __shfl_xor(L, d, 64);
      W += __shfl_xor(W, d, 64);
    }
    if (lane == 0) out[0] = (float)(L / W);
  }
}

extern "C" void kernel_launch(void* const* d_in, const int* in_sizes, int n_in,
                              void* d_out, int out_size, void* d_ws, size_t ws_size,
                              hipStream_t stream) {
  if (ws_size < OFF_END) return;
  const float* desc1 = (const float*)d_in[0];
  const float* desc2 = (const float*)d_in[1];
  const float* homo = (const float*)d_in[2];
  const void* mask = d_in[3];

  char* ws = (char*)d_ws;
  unsigned short* d1T = (unsigned short*)(ws + OFF_D1T);
  unsigned short* d2T = (unsigned short*)(ws + OFF_D2T);
  float* partial = (float*)(ws + OFF_PARTIAL);
  float* pos = (float*)(ws + OFF_POS);
  float* wv = (float*)(ws + OFF_WV);
  float* vispen = (float*)(ws + OFF_VIS);
  int4* quads = (int4*)(ws + OFF_QUAD);
  double* part = (double*)(ws + OFF_RED);
  unsigned* cnt = (unsigned*)(ws + OFF_CNT);
  float* out = (float*)d_out;

  k_pre<<<dim3(288), dim3(256), 0, stream>>>(desc1, desc2, d1T, d2T, mask, vispen, cnt);
  k_setup<<<dim3(1024, 1, 2), dim3(256), 0, stream>>>(homo, d1T, d2T, pos, wv, quads);
  k_gemm<<<dim3(1024), dim3(512), 0, stream>>>(d1T, d2T, quads, vispen, partial);
  k_redfin<<<dim3(32), dim3(256), 0, stream>>>(partial, pos, wv, part, cnt, out);
}

// Round 14
// 56.317 us; speedup vs baseline: 1.2357x; 1.0067x over previous
//
#include <hip/hip_runtime.h>

typedef __attribute__((ext_vector_type(8))) short s16x8;
typedef __attribute__((ext_vector_type(4))) float f32x4;
typedef __attribute__((ext_vector_type(4))) unsigned short u16x4;

#define FLAT 4096
#define CDIM 256
#define NB 2

// ws byte offsets
#define OFF_D1T  0u          // 4 MiB (t16-tiled bf16)
#define OFF_D2T  4194304u    // 4 MiB
#define OFF_PARTIAL 8388608u // 2*32*4096*4 = 1 MiB  (per-block column-min partials)
#define OFF_POS  9437184u    // 8192 * 4
#define OFF_WV   9469952u    // 8192 * 4
#define OFF_VIS  9502720u    // 8192 * 4
#define OFF_QUAD 9535488u    // 8192 * 16
#define OFF_RED  9666560u    // 64 doubles
#define OFF_CNT  9667072u    // done-counter
#define OFF_END  9667328u

// t16 layout: dT[b] is [FLAT/16 row-groups][CDIM/32 k-tiles][1KB tile], tile =
// [4 k-chunks(8 shorts)][16 rows][16B]; byte-identical to the LDS slab image so
// staging is ONE contiguous 1KB per global_load_lds (base + lane*16).
__device__ __forceinline__ size_t t16_off(int R, int lane) {
  return (size_t)(R >> 4) * 4096 + ((lane >> 3) * 512) + (((lane >> 1) & 3) * 128) +
         ((R & 15) * 8) + ((lane & 1) * 4);
}

__device__ __forceinline__ float bf2f(unsigned short u) {
  return __uint_as_float(((unsigned)u) << 16);
}
__device__ __forceinline__ unsigned short f2bf(float v) {
  unsigned u = __float_as_uint(v);
  return (unsigned short)((u + 0x7FFFu + ((u >> 16) & 1u)) >> 16);
}
__device__ __forceinline__ void async_g2l(const void* g, void* l) {
  __builtin_amdgcn_global_load_lds(
      (const __attribute__((address_space(1))) unsigned int*)g,
      (__attribute__((address_space(3))) unsigned int*)l,
      16, 0, 0);
}

// ---------------- pre: convert (blocks 0..255) + vis/init (blocks 256..287) ----
__global__ __launch_bounds__(256) void k_pre(const float* __restrict__ desc1,
                                             const float* __restrict__ desc2,
                                             unsigned short* __restrict__ d1T,
                                             unsigned short* __restrict__ d2T,
                                             const void* __restrict__ mask,
                                             float* __restrict__ vispen,
                                             unsigned* __restrict__ cnt) {
  __shared__ __align__(16) unsigned ldsw[64 * 128];  // 32 KB, chunk-XOR swizzled
  int bid = blockIdx.x;
  int tid = threadIdx.x;
  if (bid < 256) {
    // ---- convert: desc[b][c][n] f32 -> t16-tiled bf16 via LDS transpose ----
    int x = bid & 63, which = (bid >> 6) & 1, b = bid >> 7;
    const float* src = (which ? desc2 : desc1) + (size_t)b * CDIM * FLAT;
    unsigned short* dst = (which ? d2T : d1T) + (size_t)b * FLAT * CDIM;
    int n0 = x * 64;
    int wv = tid >> 6, lane = tid & 63;
    const float* s0 = src + n0 + lane;
#pragma unroll 2
    for (int r = 0; r < 64; r += 8) {
      int c0 = wv * 64 + r;
      float v[8];
#pragma unroll
      for (int t = 0; t < 8; ++t) v[t] = s0[(size_t)(c0 + t) * FLAT];
      unsigned pk[4];
#pragma unroll
      for (int t = 0; t < 4; ++t) pk[t] = (unsigned)f2bf(v[2 * t]) | ((unsigned)f2bf(v[2 * t + 1]) << 16);
      int pg = (c0 >> 3) ^ (lane & 31);
      *(uint4*)(ldsw + lane * 128 + pg * 4) = make_uint4(pk[0], pk[1], pk[2], pk[3]);
    }
    __syncthreads();
    int n = wv * 16 + (lane & 15);
#pragma unroll 2
    for (int it = 0; it < 8; ++it) {
      int g = it * 4 + (lane >> 4);
      uint4 d = *(const uint4*)(ldsw + n * 128 + ((g ^ (n & 31)) * 4));
      *(uint4*)(dst + ((size_t)(n0 >> 4) + wv) * 4096 + it * 512 + lane * 8) = d;
    }
  } else {
    // ---- vis: mask dtype detect + 8x8 all() -> penalty 0/5; zero counter ----
    int idx = (bid - 256) * 256 + tid;  // 32 blocks -> 8192
    if (idx == 0) *cnt = 0u;
    __shared__ int sflag;
    if (tid < 64) {
      const unsigned* mw = (const unsigned*)mask;
      int odd = 0;
#pragma unroll
      for (int t = 0; t < 16; ++t) {
        unsigned w = mw[tid * 16 + t];
        odd += (w > 1u && w != 0x3F800000u) ? 1 : 0;
      }
#pragma unroll
      for (int d = 32; d >= 1; d >>= 1) odd += __shfl_xor(odd, d, 64);
      if (tid == 0) sflag = (odd > 16) ? 1 : 0;  // 1 => byte-packed bools
    }
    __syncthreads();
    int b = idx >> 12, m = idx & 4095;
    int i = m >> 6, j = m & 63;
    bool ok = true;
    if (sflag) {
      const unsigned char* p = (const unsigned char*)mask + (size_t)b * 262144 + (size_t)(i * 8) * 512 + j * 8;
#pragma unroll
      for (int dy = 0; dy < 8; ++dy) {
        const unsigned* q = (const unsigned*)(p + (size_t)dy * 512);
        unsigned w0 = q[0], w1 = q[1];
        unsigned z0 = (w0 - 0x01010101u) & ~w0 & 0x80808080u;
        unsigned z1 = (w1 - 0x01010101u) & ~w1 & 0x80808080u;
        if (z0 | z1) ok = false;
      }
    } else {
      const unsigned* p = (const unsigned*)mask + (size_t)b * 262144 + (size_t)(i * 8) * 512 + j * 8;
#pragma unroll
      for (int dy = 0; dy < 8; ++dy) {
        const uint4* q = (const uint4*)(p + (size_t)dy * 512);
        uint4 u0 = q[0], u1 = q[1];
        if (!(u0.x && u0.y && u0.z && u0.w && u1.x && u1.y && u1.z && u1.w)) ok = false;
      }
    }
    vispen[idx] = ok ? 0.f : 5.f;
  }
}

// ---------------- setup: warp coords, wv, quad indices, pos (bilinear dot) ------
__global__ void k_setup(const float* __restrict__ homo, const unsigned short* __restrict__ d1T,
                        const unsigned short* __restrict__ d2T, float* __restrict__ pos,
                        float* __restrict__ wv, int4* __restrict__ quads) {
  int b = blockIdx.z;
  int tid = threadIdx.x;
  int wid = tid >> 6, lane = tid & 63;
  int n = blockIdx.x * 4 + wid;
  int i = n >> 6, j = n & 63;
  const float* Hm = homo + b * 9;
  float x = (float)(j * 8), y = (float)(i * 8);
  float den = Hm[6] * x + Hm[7] * y + Hm[8] + 1e-8f;
  float wxc = (Hm[0] * x + Hm[1] * y + Hm[2]) / den;
  float wyc = (Hm[3] * x + Hm[4] * y + Hm[5]) / den;

  float vv = (wyc >= 0.f && wyc < 512.f && wxc >= 0.f && wxc < 512.f) ? 1.f : 0.f;

  int ic = min(63, max(0, (int)floorf(wyc * 0.125f)));
  int jc = min(63, max(0, (int)floorf(wxc * 0.125f)));
  int ul = ic * 64 + jc;
  int ur = (ul + 1 >= FLAT) ? ul : ul + 1;
  int ll = (ul + 64 >= FLAT) ? ul : ul + 64;
  int lr = (ll + 1 >= FLAT) ? ll : ll + 1;

  float cy = fminf(fmaxf(wyc * 0.125f, 0.f), 63.f);
  float cx = fminf(fmaxf(wxc * 0.125f, 0.f), 63.f);
  float y0 = floorf(cy), x0 = floorf(cx);
  float y1 = fminf(y0 + 1.f, 63.f), x1 = fminf(x0 + 1.f, 63.f);
  float fy = cy - y0, fx = cx - x0;
  float w00 = (1.f - fy) * (1.f - fx), w01 = (1.f - fy) * fx;
  float w10 = fy * (1.f - fx), w11 = fy * fx;
  int m00 = (int)y0 * 64 + (int)x0;
  int m01 = (int)y0 * 64 + (int)x1;
  int m10 = (int)y1 * 64 + (int)x0;
  int m11 = (int)y1 * 64 + (int)x1;

  size_t base = (size_t)b * FLAT * CDIM;
  u16x4 a   = *(const u16x4*)(d1T + base + t16_off(n, lane));
  u16x4 v00 = *(const u16x4*)(d2T + base + t16_off(m00, lane));
  u16x4 v01 = *(const u16x4*)(d2T + base + t16_off(m01, lane));
  u16x4 v10 = *(const u16x4*)(d2T + base + t16_off(m10, lane));
  u16x4 v11 = *(const u16x4*)(d2T + base + t16_off(m11, lane));
  float s = 0.f;
#pragma unroll
  for (int t = 0; t < 4; ++t) {
    float vt = w00 * bf2f(v00[t]) + w01 * bf2f(v01[t]) + w10 * bf2f(v10[t]) + w11 * bf2f(v11[t]);
    s += bf2f(a[t]) * vt;
  }
#pragma unroll
  for (int d = 32; d >= 1; d >>= 1) s += __shfl_xor(s, d, 64);
  if (lane == 0) {
    int idx = b * FLAT + n;
    pos[idx] = 2.f - 2.f * s;
    wv[idx] = vv;
    quads[idx] = make_int4(ul, ur, ll, lr);
  }
}

// ---------------- min-GEMM: 256x128, 3-buf, ONE barrier per K-step --------------
// Single change vs r13: T3-minimum schedule. Per step: counted vmcnt -> ONE
// barrier -> STAGE(T+2) into buf (T-1)%3 (whose readers provably drained before
// this barrier) -> ds_read buf T%3 -> lgkmcnt(0) -> MFMA. Barriers/block 16->8;
// no post-MFMA drain. vmcnt ledger: <=6 outstanding at step top; vmcnt(3)
// retires exactly stage T; step 7 uses vmcnt(0).
__global__ __launch_bounds__(512, 4) void k_gemm(const unsigned short* __restrict__ d1T,
                                                 const unsigned short* __restrict__ d2T,
                                                 const int4* __restrict__ quads,
                                                 const float* __restrict__ vispen,
                                                 float* __restrict__ partial) {
  __shared__ __align__(16) char lds[3][24576];  // per buf: A tiles 0..15 (16KB), B tiles 0..7 (8KB)
  // XCD-chunked swizzle (nwg=1024, %8==0 -> bijective)
  int lin = blockIdx.x;
  int id = (lin & 7) * 128 + (lin >> 3);
  int b = id >> 9;
  int mn = id & 511;
  int m0 = (mn & 31) << 7;   // cols (desc2), 32 m-blocks of 128
  int n0 = (mn >> 5) << 8;   // rows (desc1), 16 n-blocks of 256
  int tid = threadIdx.x;
  int wid = tid >> 6, lane = tid & 63;
  int wr = wid >> 1, wc = wid & 1;  // 4x2 wave grid of 64x64 tiles
  int lg = lane >> 4, ll16 = lane & 15;

  const unsigned short* Ab = d1T + (size_t)b * FLAT * CDIM;
  const unsigned short* Bb = d2T + (size_t)b * FLAT * CDIM;

  // wave wid stages tiles idx = wid*3 .. wid*3+2 (24 total: 16 A + 8 B);
  // each source is a CONTIGUOUS 1KB t16 tile: base + lane*16B.
  const unsigned short* srcq[3];
  int ldsoff[3];
#pragma unroll
  for (int q = 0; q < 3; ++q) {
    int idx = wid * 3 + q;      // 0..23
    int isA = idx < 16;
    int s = isA ? idx : idx - 16;
    int rg = (((isA ? n0 : m0)) >> 4) + s;
    srcq[q] = (isA ? Ab : Bb) + (size_t)rg * 4096 + lane * 8;
    ldsoff[q] = (isA ? 0 : 16384) + s * 1024;
  }

  f32x4 acc[4][4] = {};

#define STAGE(t, p)                                            \
  {                                                            \
    _Pragma("unroll") for (int q = 0; q < 3; ++q)              \
        async_g2l(srcq[q] + (t) * 512, &lds[p][ldsoff[q]]);    \
  }

#define KSTEP(T, WN)                                                                \
  {                                                                                 \
    asm volatile("s_waitcnt vmcnt(" #WN ")" ::: "memory");                          \
    __builtin_amdgcn_s_barrier();                                                   \
    if ((T) < 6) STAGE((T) + 2, ((T) + 2) % 3);                                     \
    const char* base_ = lds[(T) % 3];                                               \
    s16x8 af[4], bf[4];                                                             \
    _Pragma("unroll") for (int mi = 0; mi < 4; ++mi)                                \
        af[mi] = *(const s16x8*)(base_ + (wr * 4 + mi) * 1024 + lane * 16);         \
    _Pragma("unroll") for (int ni = 0; ni < 4; ++ni)                                \
        bf[ni] = *(const s16x8*)(base_ + 16384 + (wc * 4 + ni) * 1024 + lane * 16); \
    asm volatile("s_waitcnt lgkmcnt(0)" ::: "memory");                              \
    _Pragma("unroll") for (int mi = 0; mi < 4; ++mi)                                \
      _Pragma("unroll") for (int ni = 0; ni < 4; ++ni)                              \
          acc[mi][ni] =                                                             \
              __builtin_amdgcn_mfma_f32_16x16x32_bf16(af[mi], bf[ni], acc[mi][ni], 0, 0, 0); \
  }

  STAGE(0, 0);
  STAGE(1, 1);
  KSTEP(0, 3) KSTEP(1, 3) KSTEP(2, 3) KSTEP(3, 3)
  KSTEP(4, 3) KSTEP(5, 3) KSTEP(6, 3) KSTEP(7, 0)
#undef KSTEP
#undef STAGE

  // epilogue: penalties + column-min; cross-wave combine in LDS; one plain
  // coalesced store per row (no atomics). red overlays lds[0] (disjoint from
  // lds[1] read in step 7; per-wave red slots disjoint; __syncthreads before read).
  const int4* qB = quads + b * FLAT;
  const float* vB = vispen + b * FLAT;
  float* red = (float*)lds;  // 256 rows x 2 col-halves
  float pv[4];
#pragma unroll
  for (int ni = 0; ni < 4; ++ni) pv[ni] = vB[m0 + wc * 64 + ni * 16 + ll16];
#pragma unroll
  for (int mi = 0; mi < 4; ++mi) {
    int rowBase = wr * 64 + mi * 16 + lg * 4;
    float rm[4] = {1e30f, 1e30f, 1e30f, 1e30f};
    int4 q0 = qB[n0 + rowBase + 0];
    int4 q1 = qB[n0 + rowBase + 1];
    int4 q2 = qB[n0 + rowBase + 2];
    int4 q3 = qB[n0 + rowBase + 3];
#pragma unroll
    for (int ni = 0; ni < 4; ++ni) {
      int gm = m0 + wc * 64 + ni * 16 + ll16;
      f32x4 a = acc[mi][ni];
      float v0 = 2.f - 2.f * a[0] + pv[ni] + ((gm == q0.x || gm == q0.y || gm == q0.z || gm == q0.w) ? 5.f : 0.f);
      float v1 = 2.f - 2.f * a[1] + pv[ni] + ((gm == q1.x || gm == q1.y || gm == q1.z || gm == q1.w) ? 5.f : 0.f);
      float v2 = 2.f - 2.f * a[2] + pv[ni] + ((gm == q2.x || gm == q2.y || gm == q2.z || gm == q2.w) ? 5.f : 0.f);
      float v3 = 2.f - 2.f * a[3] + pv[ni] + ((gm == q3.x || gm == q3.y || gm == q3.z || gm == q3.w) ? 5.f : 0.f);
      rm[0] = fminf(rm[0], v0);
      rm[1] = fminf(rm[1], v1);
      rm[2] = fminf(rm[2], v2);
      rm[3] = fminf(rm[3], v3);
    }
#pragma unroll
    for (int r = 0; r < 4; ++r) {
      float v = rm[r];
#pragma unroll
      for (int d = 1; d < 16; d <<= 1) v = fminf(v, __shfl_xor(v, d, 64));
      if (ll16 == 0) red[(rowBase + r) * 2 + wc] = v;
    }
  }
  __syncthreads();
  if ((wid & 1) == 0) {  // waves 0,2,4,6 -> rows wr*64..+63
    int row = wr * 64 + lane;
    float v = fminf(red[row * 2], red[row * 2 + 1]);
    partial[((size_t)(b * 32 + (m0 >> 7))) * FLAT + n0 + row] = v;
  }
}

// ---------------- reduce partials + loss; last block finalizes ----------------
__global__ void k_redfin(const float* __restrict__ partial, const float* __restrict__ pos,
                         const float* __restrict__ wv, double* __restrict__ part,
                         unsigned* __restrict__ cnt, float* __restrict__ out) {
  int tid = threadIdx.x;
  int bid = blockIdx.x;
  int idx = bid * 256 + tid;  // grid 32 -> 8192
  int wid = tid >> 6, lane = tid & 63;
  int b = idx >> 12, nl = idx & 4095;
  const float* ps = partial + (size_t)b * 32 * FLAT + nl;
  float neg = 1e30f;
#pragma unroll
  for (int s = 0; s < 32; ++s) neg = fminf(neg, ps[(size_t)s * FLAT]);
  float p = pos[idx], w = wv[idx];
  float t = fmaxf(p - neg + 1.f, 0.f);
  double aL = (double)(t * t) * (double)w;
  double aW = (double)w;
#pragma unroll
  for (int d = 32; d >= 1; d >>= 1) {
    aL += __shfl_xor(aL, d, 64);
    aW += __shfl_xor(aW, d, 64);
  }
  __shared__ double red[8];
  __shared__ int lastFlag;
  if (lane == 0) { red[wid * 2] = aL; red[wid * 2 + 1] = aW; }
  __syncthreads();
  if (tid == 0) {
    double L = 0.0, W = 0.0;
#pragma unroll
    for (int u = 0; u < 4; ++u) { L += red[u * 2]; W += red[u * 2 + 1]; }
    part[bid * 2] = L;
    part[bid * 2 + 1] = W;
    __threadfence();
    unsigned old = atomicAdd(cnt, 1u);
    lastFlag = (old == 31u) ? 1 : 0;
  }
  __syncthreads();
  if (lastFlag && wid == 0) {
    double L = 0.0, W = 0.0;
    if (lane < 32) { L = part[2 * lane]; W = part[2 * lane + 1]; }
#pragma unroll
    for (int d = 16; d >= 1; d >>= 1) {
      L += __shfl_xor(L, d, 64);
      W += __shfl_xor(W, d, 64);
    }
    if (lane == 0) out[0] = (float)(L / W);
  }
}

extern "C" void kernel_launch(void* const* d_in, const int* in_sizes, int n_in,
                              void* d_out, int out_size, void* d_ws, size_t ws_size,
                              hipStream_t stream) {
  if (ws_size < OFF_END) return;
  const float* desc1 = (const float*)d_in[0];
  const float* desc2 = (const float*)d_in[1];
  const float* homo = (const float*)d_in[2];
  const void* mask = d_in[3];

  char* ws = (char*)d_ws;
  unsigned short* d1T = (unsigned short*)(ws + OFF_D1T);
  unsigned short* d2T = (unsigned short*)(ws + OFF_D2T);
  float* partial = (float*)(ws + OFF_PARTIAL);
  float* pos = (float*)(ws + OFF_POS);
  float* wv = (float*)(ws + OFF_WV);
  float* vispen = (float*)(ws + OFF_VIS);
  int4* quads = (int4*)(ws + OFF_QUAD);
  double* part = (double*)(ws + OFF_RED);
  unsigned* cnt = (unsigned*)(ws + OFF_CNT);
  float* out = (float*)d_out;

  k_pre<<<dim3(288), dim3(256), 0, stream>>>(desc1, desc2, d1T, d2T, mask, vispen, cnt);
  k_setup<<<dim3(1024, 1, 2), dim3(256), 0, stream>>>(homo, d1T, d2T, pos, wv, quads);
  k_gemm<<<dim3(1024), dim3(512), 0, stream>>>(d1T, d2T, quads, vispen, partial);
  k_redfin<<<dim3(32), dim3(256), 0, stream>>>(partial, pos, wv, part, cnt, out);
}